// Round 1
// baseline (6953.744 us; speedup 1.0000x reference)
//
#include <hip/hip_runtime.h>

// CatanGNN: 2-layer heterogeneous GATv2 on MI355X. fp32 correctness-first build.
// Node types: 0=t 1=v 2=e, N=100000 each. 9 relations, E=300000 edges each.
// HID=128, HEADS=2, C=64. Relation r: src type ST[r], dst type DT[r].

#define NN 100000
#define NE 300000
#define NH (NN * 128)

__device__ __forceinline__ unsigned fenc(float f) {
    unsigned u = __float_as_uint(f);
    return (u & 0x80000000u) ? ~u : (u | 0x80000000u);
}
__device__ __forceinline__ float fdec(unsigned u) {
    return (u & 0x80000000u) ? __uint_as_float(u ^ 0x80000000u) : __uint_as_float(~u);
}

// h = x @ W + b ; x:[M,16] W:[16,128] b:[128]. One wave per row, lane -> cols {c, c+64}.
__global__ void inproj_k(const float* __restrict__ X, const float* __restrict__ W,
                         const float* __restrict__ b, float* __restrict__ H, int M) {
    int w = (int)((blockIdx.x * blockDim.x + threadIdx.x) >> 6);
    int lane = threadIdx.x & 63;
    if (w >= M) return;
    const float* x = X + (long)w * 16;
    float a0 = 0.f, a1 = 0.f;
#pragma unroll
    for (int k = 0; k < 16; ++k) {
        float xv = x[k];
        a0 = fmaf(xv, W[k * 128 + lane], a0);
        a1 = fmaf(xv, W[k * 128 + 64 + lane], a1);
    }
    H[(long)w * 128 + lane] = a0 + b[lane];
    H[(long)w * 128 + 64 + lane] = a1 + b[64 + lane];
}

// Y = X @ W ; X:[M,128] W:[128,128] row-major. Block: 256 thr, 64 rows x 128 cols.
// Thread (ty=tid/32, tx=tid%32): 8 rows x 4 cols. W staged fully in LDS (64KB).
__global__ __launch_bounds__(256) void gemm128_k(const float* __restrict__ X,
                                                 const float* __restrict__ W,
                                                 float* __restrict__ Y, int M) {
    __shared__ float Ws[128 * 128];
    int tid = threadIdx.x;
    const float4* W4 = (const float4*)W;
    float4* Ws4 = (float4*)Ws;
#pragma unroll
    for (int i = 0; i < 16; ++i) Ws4[i * 256 + tid] = W4[i * 256 + tid];
    __syncthreads();
    int tx = tid & 31, ty = tid >> 5;
    long row0 = (long)blockIdx.x * 64 + ty * 8;
    const float* Xp = X + row0 * 128;
    int c0 = tx * 4;
    float acc[8][4];
#pragma unroll
    for (int i = 0; i < 8; ++i)
#pragma unroll
        for (int j = 0; j < 4; ++j) acc[i][j] = 0.f;
    for (int k0 = 0; k0 < 128; k0 += 4) {
        float4 xv[8];
#pragma unroll
        for (int i = 0; i < 8; ++i) xv[i] = *(const float4*)(Xp + i * 128 + k0);
#pragma unroll
        for (int kk = 0; kk < 4; ++kk) {
            float4 wv = *(const float4*)(Ws + (k0 + kk) * 128 + c0);
#pragma unroll
            for (int i = 0; i < 8; ++i) {
                float xk = (&xv[i].x)[kk];
                acc[i][0] = fmaf(xk, wv.x, acc[i][0]);
                acc[i][1] = fmaf(xk, wv.y, acc[i][1]);
                acc[i][2] = fmaf(xk, wv.z, acc[i][2]);
                acc[i][3] = fmaf(xk, wv.w, acc[i][3]);
            }
        }
    }
#pragma unroll
    for (int i = 0; i < 8; ++i) {
        long r = row0 + i;
        if (r < M) *(float4*)(Y + r * 128 + c0) = *(float4*)acc[i];
    }
}

// Per-edge attention logits + scatter-max. One wave per edge; lane c covers channel c of
// both heads (cols c and 64+c). e_h = sum_c lrelu(gl+gr)*att[h][c].
__global__ void score_k(const float* __restrict__ PL, const float* __restrict__ PR,
                        const int* __restrict__ ei, const float* __restrict__ att,
                        float* __restrict__ esc, unsigned* __restrict__ emax, int E) {
    int w = (int)((blockIdx.x * blockDim.x + threadIdx.x) >> 6);
    int lane = threadIdx.x & 63;
    if (w >= E) return;
    int s = ei[w], d = ei[E + w];
    const float* gl = PL + (long)s * 128;
    const float* gr = PR + (long)d * 128;
    float v0 = gl[lane] + gr[lane];
    float v1 = gl[64 + lane] + gr[64 + lane];
    v0 = (v0 > 0.f ? v0 : 0.2f * v0) * att[lane];
    v1 = (v1 > 0.f ? v1 : 0.2f * v1) * att[64 + lane];
#pragma unroll
    for (int off = 32; off; off >>= 1) {
        v0 += __shfl_xor(v0, off);
        v1 += __shfl_xor(v1, off);
    }
    if (lane == 0) {
        esc[2 * w] = v0;
        esc[2 * w + 1] = v1;
        atomicMax(&emax[2 * d], fenc(v0));
        atomicMax(&emax[2 * d + 1], fenc(v1));
    }
}

// p = exp(e - max[dst]); scatter-sum denominators. Thread per (edge, head).
__global__ void expsum_k(float* __restrict__ esc, const int* __restrict__ ei,
                         const unsigned* __restrict__ emax, float* __restrict__ denom, int E) {
    int i = blockIdx.x * blockDim.x + threadIdx.x;
    if (i >= 2 * E) return;
    int e = i >> 1, h = i & 1;
    int d = ei[E + e];
    float m = fdec(emax[2 * d + h]);
    float p = expf(esc[i] - m);
    esc[i] = p;
    atomicAdd(&denom[2 * d + h], p);
}

// out[dst] += alpha * gl[src]. One wave per edge, 2 atomics per lane.
__global__ void aggr_k(const float* __restrict__ PL, const float* __restrict__ esc,
                       const float* __restrict__ denom, const int* __restrict__ ei,
                       float* __restrict__ out, int E) {
    int w = (int)((blockIdx.x * blockDim.x + threadIdx.x) >> 6);
    int lane = threadIdx.x & 63;
    if (w >= E) return;
    int s = ei[w], d = ei[E + w];
    float p0 = esc[2 * w], p1 = esc[2 * w + 1];
    float d0 = denom[2 * d], d1 = denom[2 * d + 1];
    float a0 = p0 / (d0 + 1e-16f), a1 = p1 / (d1 + 1e-16f);
    const float* gl = PL + (long)s * 128;
    atomicAdd(&out[(long)d * 128 + lane], a0 * gl[lane]);
    atomicAdd(&out[(long)d * 128 + 64 + lane], a1 * gl[64 + lane]);
}

// out[i] = (acc[i] + bc[r0][col]+bc[r1][col]+bc[r2][col]), optional relu. In-place safe.
__global__ void finalize_k(const float* __restrict__ acc, const float* __restrict__ bc,
                           int r0, int r1, int r2, float* __restrict__ out, int n, int relu) {
    int i = blockIdx.x * blockDim.x + threadIdx.x;
    if (i >= n) return;
    int col = i & 127;
    float b = bc[r0 * 128 + col] + bc[r1 * 128 + col] + bc[r2 * 128 + col];
    float v = acc[i] + b;
    out[i] = relu ? fmaxf(v, 0.f) : v;
}

__global__ void sentinel_k(float* out) { out[0] = 123456.0f; }

extern "C" void kernel_launch(void* const* d_in, const int* in_sizes, int n_in,
                              void* d_out, int out_size, void* d_ws, size_t ws_size,
                              hipStream_t stream) {
    const float* xt = (const float*)d_in[0];
    const float* xv = (const float*)d_in[1];
    const float* xe = (const float*)d_in[2];
    const int* ei[9];
    for (int r = 0; r < 9; ++r) ei[r] = (const int*)d_in[3 + r];
    const float* Win[3] = {(const float*)d_in[12], (const float*)d_in[14], (const float*)d_in[16]};
    const float* bin[3] = {(const float*)d_in[13], (const float*)d_in[15], (const float*)d_in[17]};
    const float* Wl[2] = {(const float*)d_in[18], (const float*)d_in[22]};
    const float* Wr[2] = {(const float*)d_in[19], (const float*)d_in[23]};
    const float* att[2] = {(const float*)d_in[20], (const float*)d_in[24]};
    const float* bc[2] = {(const float*)d_in[21], (const float*)d_in[25]};

    // workspace layout (floats): h[3] | projL | projR | emax(2N u32) | denom(2N) | esc(2E)
    size_t need = ((size_t)5 * NH + 4 * NN + 2 * NE) * 4;
    if (ws_size < need) {  // distinctive failure signature instead of memory corruption
        hipMemsetAsync(d_out, 0, (size_t)out_size * 4, stream);
        sentinel_k<<<1, 1, 0, stream>>>((float*)d_out);
        return;
    }
    float* ws = (float*)d_ws;
    float* h[3] = {ws, ws + NH, ws + 2 * (size_t)NH};
    float* projL = ws + 3 * (size_t)NH;
    float* projR = ws + 4 * (size_t)NH;
    unsigned* emax = (unsigned*)(ws + 5 * (size_t)NH);
    float* denom = ws + 5 * (size_t)NH + 2 * NN;
    float* esc = ws + 5 * (size_t)NH + 4 * NN;
    float* outAcc[3] = {(float*)d_out, (float*)d_out + NH, (float*)d_out + 2 * (size_t)NH};

    static const int ST[9] = {0, 0, 1, 0, 2, 1, 2, 1, 2};
    static const int DT[9] = {0, 1, 0, 2, 0, 2, 1, 1, 2};
    // relations feeding each dst type (for summed biases)
    static const int RT[3][3] = {{0, 2, 4}, {1, 6, 7}, {3, 5, 8}};

    const float* xin[3] = {xt, xv, xe};
    for (int T = 0; T < 3; ++T)
        inproj_k<<<(NN + 3) / 4, 256, 0, stream>>>(xin[T], Win[T], bin[T], h[T], NN);

    int gemmGrid = (NN + 63) / 64;
    int edgeGrid = (NE + 3) / 4;
    for (int l = 0; l < 2; ++l) {
        hipMemsetAsync(d_out, 0, (size_t)3 * NH * 4, stream);
        for (int r = 0; r < 9; ++r) {
            hipMemsetAsync(emax, 0, (size_t)4 * NN * 4, stream);  // emax identity + denom zero
            gemm128_k<<<gemmGrid, 256, 0, stream>>>(h[ST[r]], Wl[l] + (size_t)r * 16384, projL, NN);
            gemm128_k<<<gemmGrid, 256, 0, stream>>>(h[DT[r]], Wr[l] + (size_t)r * 16384, projR, NN);
            score_k<<<edgeGrid, 256, 0, stream>>>(projL, projR, ei[r], att[l] + (size_t)r * 128,
                                                  esc, emax, NE);
            expsum_k<<<(2 * NE + 255) / 256, 256, 0, stream>>>(esc, ei[r], emax, denom, NE);
            aggr_k<<<edgeGrid, 256, 0, stream>>>(projL, esc, denom, ei[r], outAcc[DT[r]], NE);
        }
        for (int T = 0; T < 3; ++T) {
            if (l == 0)
                finalize_k<<<NH / 256, 256, 0, stream>>>(outAcc[T], bc[0], RT[T][0], RT[T][1],
                                                         RT[T][2], h[T], NH, 1);
            else
                finalize_k<<<NH / 256, 256, 0, stream>>>(outAcc[T], bc[1], RT[T][0], RT[T][1],
                                                         RT[T][2], outAcc[T], NH, 0);
        }
    }
}

// Round 2
// 4738.295 us; speedup vs baseline: 1.4676x; 1.4676x over previous
//
#include <hip/hip_runtime.h>

// CatanGNN: 2-layer heterogeneous GATv2 on MI355X.
// Round 2: atomic-free scatter softmax/aggregation via once-per-call CSR +
// fused flash-style per-dst-node GAT kernel (online softmax, single gather pass).
// Node types: 0=t 1=v 2=e, N=100000 each. 9 relations, E=300000 edges each.
// HID=128, HEADS=2, C=64.

#define NN 100000
#define NE 300000
#define NH (NN * 128)
#define NB 391  // ceil(NN / 256)

struct EPtrs { const int* p[9]; };

// ---------------- projections ----------------

// h = x @ W + b ; x:[M,16] W:[16,128]. One wave per row, lane -> cols {c, c+64}.
__global__ void inproj_k(const float* __restrict__ X, const float* __restrict__ W,
                         const float* __restrict__ b, float* __restrict__ H, int M) {
    int w = (int)((blockIdx.x * blockDim.x + threadIdx.x) >> 6);
    int lane = threadIdx.x & 63;
    if (w >= M) return;
    const float* x = X + (long)w * 16;
    float a0 = 0.f, a1 = 0.f;
#pragma unroll
    for (int k = 0; k < 16; ++k) {
        float xv = x[k];
        a0 = fmaf(xv, W[k * 128 + lane], a0);
        a1 = fmaf(xv, W[k * 128 + 64 + lane], a1);
    }
    H[(long)w * 128 + lane] = a0 + b[lane];
    H[(long)w * 128 + 64 + lane] = a1 + b[64 + lane];
}

// Y = X @ W ; X:[M,128] W:[128,128]. 256 thr: 64 rows x 128 cols, W in LDS.
__global__ __launch_bounds__(256) void gemm128_k(const float* __restrict__ X,
                                                 const float* __restrict__ W,
                                                 float* __restrict__ Y, int M) {
    __shared__ float Ws[128 * 128];
    int tid = threadIdx.x;
    const float4* W4 = (const float4*)W;
    float4* Ws4 = (float4*)Ws;
#pragma unroll
    for (int i = 0; i < 16; ++i) Ws4[i * 256 + tid] = W4[i * 256 + tid];
    __syncthreads();
    int tx = tid & 31, ty = tid >> 5;
    long row0 = (long)blockIdx.x * 64 + ty * 8;
    const float* Xp = X + row0 * 128;
    int c0 = tx * 4;
    float acc[8][4];
#pragma unroll
    for (int i = 0; i < 8; ++i)
#pragma unroll
        for (int j = 0; j < 4; ++j) acc[i][j] = 0.f;
    for (int k0 = 0; k0 < 128; k0 += 4) {
        float4 xv[8];
#pragma unroll
        for (int i = 0; i < 8; ++i) xv[i] = *(const float4*)(Xp + i * 128 + k0);
#pragma unroll
        for (int kk = 0; kk < 4; ++kk) {
            float4 wv = *(const float4*)(Ws + (k0 + kk) * 128 + c0);
#pragma unroll
            for (int i = 0; i < 8; ++i) {
                float xk = (&xv[i].x)[kk];
                acc[i][0] = fmaf(xk, wv.x, acc[i][0]);
                acc[i][1] = fmaf(xk, wv.y, acc[i][1]);
                acc[i][2] = fmaf(xk, wv.z, acc[i][2]);
                acc[i][3] = fmaf(xk, wv.w, acc[i][3]);
            }
        }
    }
#pragma unroll
    for (int i = 0; i < 8; ++i) {
        long r = row0 + i;
        if (r < M) *(float4*)(Y + r * 128 + c0) = *(float4*)acc[i];
    }
}

// ---------------- CSR build (once per call, reused by both layers) ----------------

__global__ void count_k(EPtrs ep, int* __restrict__ deg) {
    int r = blockIdx.y;
    int e = blockIdx.x * 256 + threadIdx.x;
    if (e >= NE) return;
    int d = ep.p[r][NE + e];
    atomicAdd(&deg[r * NN + d], 1);
}

__global__ void scanA_k(const int* __restrict__ deg, int* __restrict__ bsum) {
    __shared__ int sm[256];
    int r = blockIdx.y, b = blockIdx.x, t = threadIdx.x;
    int i = b * 256 + t;
    sm[t] = (i < NN) ? deg[r * NN + i] : 0;
    __syncthreads();
#pragma unroll
    for (int o = 128; o; o >>= 1) {
        if (t < o) sm[t] += sm[t + o];
        __syncthreads();
    }
    if (t == 0) bsum[r * NB + b] = sm[0];
}

__global__ void scanB_k(int* __restrict__ bsum) {  // exclusive scan of NB per relation
    __shared__ int sm[512];
    int r = blockIdx.x, t = threadIdx.x;
    int v = (t < NB) ? bsum[r * NB + t] : 0;
    sm[t] = v;
    __syncthreads();
    for (int o = 1; o < 512; o <<= 1) {
        int x = (t >= o) ? sm[t - o] : 0;
        __syncthreads();
        sm[t] += x;
        __syncthreads();
    }
    if (t < NB) bsum[r * NB + t] = sm[t] - v;
}

// rowp = exclusive scan of deg (+block offset); cursor (aliases deg) = same.
__global__ void scanC_k(int* __restrict__ deg, const int* __restrict__ bsum,
                        int* __restrict__ rowp) {
    __shared__ int sm[256];
    int r = blockIdx.y, b = blockIdx.x, t = threadIdx.x;
    int i = b * 256 + t;
    int v = (i < NN) ? deg[r * NN + i] : 0;
    sm[t] = v;
    __syncthreads();
    for (int o = 1; o < 256; o <<= 1) {
        int x = (t >= o) ? sm[t - o] : 0;
        __syncthreads();
        sm[t] += x;
        __syncthreads();
    }
    int excl = sm[t] - v + bsum[r * NB + b];
    if (i < NN) {
        rowp[r * (NN + 1) + i] = excl;
        deg[r * NN + i] = excl;  // becomes scatter cursor
        if (i == NN - 1) rowp[r * (NN + 1) + NN] = excl + v;
    }
}

__global__ void scat_k(EPtrs ep, int* __restrict__ cursor, int* __restrict__ csrc) {
    int r = blockIdx.y;
    int e = blockIdx.x * 256 + threadIdx.x;
    if (e >= NE) return;
    int s = ep.p[r][e], d = ep.p[r][NE + e];
    int pos = atomicAdd(&cursor[r * NN + d], 1);
    csrc[(long)r * NE + pos] = s;
}

// ---------------- fused GATv2 edge pass (score + online softmax + aggregate) --------

// One wave per dst node d; lane c handles channel c of head0 (col c) and head1 (col 64+c).
__global__ void gat_k(const float* __restrict__ PL, const float* __restrict__ PR,
                      const int* __restrict__ rowp, const int* __restrict__ csrc,
                      const float* __restrict__ att, float* __restrict__ out) {
    int w = (int)((blockIdx.x * blockDim.x + threadIdx.x) >> 6);
    int c = threadIdx.x & 63;
    if (w >= NN) return;
    int beg = rowp[w], end = rowp[w + 1];
    if (beg == end) return;
    float gr0 = PR[(long)w * 128 + c], gr1 = PR[(long)w * 128 + 64 + c];
    float at0 = att[c], at1 = att[64 + c];
    float m0 = -1e30f, m1 = -1e30f, s0 = 0.f, s1 = 0.f, a0 = 0.f, a1 = 0.f;
    for (int i = beg; i < end; ++i) {
        int s = csrc[i];  // wave-uniform -> broadcast
        float gl0 = PL[(long)s * 128 + c], gl1 = PL[(long)s * 128 + 64 + c];
        float v0 = gl0 + gr0;
        v0 = (v0 > 0.f ? v0 : 0.2f * v0) * at0;
        float v1 = gl1 + gr1;
        v1 = (v1 > 0.f ? v1 : 0.2f * v1) * at1;
#pragma unroll
        for (int o = 32; o; o >>= 1) {
            v0 += __shfl_xor(v0, o);
            v1 += __shfl_xor(v1, o);
        }
        float mn0 = fmaxf(m0, v0), sc0 = __expf(m0 - mn0), p0 = __expf(v0 - mn0);
        s0 = s0 * sc0 + p0; a0 = a0 * sc0 + p0 * gl0; m0 = mn0;
        float mn1 = fmaxf(m1, v1), sc1 = __expf(m1 - mn1), p1 = __expf(v1 - mn1);
        s1 = s1 * sc1 + p1; a1 = a1 * sc1 + p1 * gl1; m1 = mn1;
    }
    out[(long)w * 128 + c] += a0 / (s0 + 1e-16f);
    out[(long)w * 128 + 64 + c] += a1 / (s1 + 1e-16f);
}

// out[i] = acc[i] + bc[r0][col]+bc[r1][col]+bc[r2][col], optional relu. In-place safe.
__global__ void finalize_k(const float* __restrict__ acc, const float* __restrict__ bc,
                           int r0, int r1, int r2, float* __restrict__ out, int n, int relu) {
    int i = blockIdx.x * blockDim.x + threadIdx.x;
    if (i >= n) return;
    int col = i & 127;
    float b = bc[r0 * 128 + col] + bc[r1 * 128 + col] + bc[r2 * 128 + col];
    float v = acc[i] + b;
    out[i] = relu ? fmaxf(v, 0.f) : v;
}

__global__ void sentinel_k(float* out) { out[0] = 123456.0f; }

extern "C" void kernel_launch(void* const* d_in, const int* in_sizes, int n_in,
                              void* d_out, int out_size, void* d_ws, size_t ws_size,
                              hipStream_t stream) {
    const float* xin[3] = {(const float*)d_in[0], (const float*)d_in[1], (const float*)d_in[2]};
    EPtrs ep;
    for (int r = 0; r < 9; ++r) ep.p[r] = (const int*)d_in[3 + r];
    const float* Win[3] = {(const float*)d_in[12], (const float*)d_in[14], (const float*)d_in[16]};
    const float* bin[3] = {(const float*)d_in[13], (const float*)d_in[15], (const float*)d_in[17]};
    const float* Wl[2] = {(const float*)d_in[18], (const float*)d_in[22]};
    const float* Wr[2] = {(const float*)d_in[19], (const float*)d_in[23]};
    const float* att[2] = {(const float*)d_in[20], (const float*)d_in[24]};
    const float* bc[2] = {(const float*)d_in[21], (const float*)d_in[25]};

    // ws layout: h[3] (3*NH f) | projL (NH) | projR (NH) | ints: deg/cursor 9*NN |
    //            bsum 9*NB | rowp 9*(NN+1) | csrc 9*NE
    size_t fl = (size_t)5 * NH;
    size_t ints = (size_t)9 * NN + (size_t)9 * NB + (size_t)9 * (NN + 1) + (size_t)9 * NE;
    size_t need = (fl + ints) * 4;
    if (ws_size < need) {
        hipMemsetAsync(d_out, 0, (size_t)out_size * 4, stream);
        sentinel_k<<<1, 1, 0, stream>>>((float*)d_out);
        return;
    }
    float* ws = (float*)d_ws;
    float* h[3] = {ws, ws + NH, ws + 2 * (size_t)NH};
    float* projL = ws + 3 * (size_t)NH;
    float* projR = ws + 4 * (size_t)NH;
    int* deg = (int*)(ws + fl);          // aliases cursor after scanC
    int* bsum = deg + (size_t)9 * NN;
    int* rowp = bsum + (size_t)9 * NB;
    int* csrc = rowp + (size_t)9 * (NN + 1);
    float* outAcc[3] = {(float*)d_out, (float*)d_out + NH, (float*)d_out + 2 * (size_t)NH};

    static const int ST[9] = {0, 0, 1, 0, 2, 1, 2, 1, 2};
    static const int DT[9] = {0, 1, 0, 2, 0, 2, 1, 1, 2};
    static const int RT[3][3] = {{0, 2, 4}, {1, 6, 7}, {3, 5, 8}};  // relations per dst type

    // input projections
    for (int T = 0; T < 3; ++T)
        inproj_k<<<(NN + 3) / 4, 256, 0, stream>>>(xin[T], Win[T], bin[T], h[T], NN);

    // CSR build for all 9 relations (edges identical across layers)
    hipMemsetAsync(deg, 0, (size_t)9 * NN * 4, stream);
    dim3 eg((NE + 255) / 256, 9), ng(NB, 9);
    count_k<<<eg, 256, 0, stream>>>(ep, deg);
    scanA_k<<<ng, 256, 0, stream>>>(deg, bsum);
    scanB_k<<<9, 512, 0, stream>>>(bsum);
    scanC_k<<<ng, 256, 0, stream>>>(deg, bsum, rowp);
    scat_k<<<eg, 256, 0, stream>>>(ep, deg, csrc);

    int gemmGrid = (NN + 63) / 64;
    int nodeGrid = (NN + 3) / 4;
    for (int l = 0; l < 2; ++l) {
        hipMemsetAsync(d_out, 0, (size_t)3 * NH * 4, stream);
        for (int r = 0; r < 9; ++r) {
            gemm128_k<<<gemmGrid, 256, 0, stream>>>(h[ST[r]], Wl[l] + (size_t)r * 16384, projL, NN);
            gemm128_k<<<gemmGrid, 256, 0, stream>>>(h[DT[r]], Wr[l] + (size_t)r * 16384, projR, NN);
            gat_k<<<nodeGrid, 256, 0, stream>>>(projL, projR, rowp + (size_t)r * (NN + 1),
                                                csrc + (size_t)r * NE, att[l] + (size_t)r * 128,
                                                outAcc[DT[r]]);
        }
        for (int T = 0; T < 3; ++T) {
            if (l == 0)
                finalize_k<<<NH / 256, 256, 0, stream>>>(outAcc[T], bc[0], RT[T][0], RT[T][1],
                                                         RT[T][2], h[T], NH, 1);
            else
                finalize_k<<<NH / 256, 256, 0, stream>>>(outAcc[T], bc[1], RT[T][0], RT[T][1],
                                                         RT[T][2], outAcc[T], NH, 0);
        }
    }
}

// Round 3
// 2032.680 us; speedup vs baseline: 3.4210x; 2.3311x over previous
//
#include <hip/hip_runtime.h>

// CatanGNN: 2-layer hetero GATv2 on MI355X (gfx950).
// Round 3: bf16 intermediates + MFMA GEMM (16x16x32_bf16) + fused per-dst-type
// 3-relation flash-GAT kernel (no accumulator RMW, no memsets, bias/relu folded).
// N=100000/type, E=300000/relation, HID=128, HEADS=2, C=64.

#define NN 100000
#define NE 300000
#define NH (NN * 128)
#define NB 391  // ceil(NN/256)

typedef __attribute__((ext_vector_type(8))) short short8;   // 8 bf16 (4 VGPRs)
typedef __attribute__((ext_vector_type(4))) float f32x4;    // MFMA acc

__device__ __forceinline__ float bf2f(unsigned short h) {
    return __uint_as_float(((unsigned)h) << 16);
}
__device__ __forceinline__ unsigned short f2bf(float x) {  // RNE
    unsigned u = __float_as_uint(x);
    return (unsigned short)((u + 0x7FFFu + ((u >> 16) & 1u)) >> 16);
}

struct EPtrs { const int* p[9]; };
struct G6 { const unsigned short* A[6]; const float* W[6]; unsigned short* O[6]; };
struct GatA {
    const unsigned short* PL[3];
    const unsigned short* PR[3];
    const int* rowp[3];
    const int* csrc[3];
    const float* att[3];
    const float* bias[3];
};

// ---------------- input projection: h = x@W + b -> bf16 ----------------
__global__ void inproj_k(const float* __restrict__ X, const float* __restrict__ W,
                         const float* __restrict__ b, unsigned short* __restrict__ H, int M) {
    int w = (int)((blockIdx.x * blockDim.x + threadIdx.x) >> 6);
    int lane = threadIdx.x & 63;
    if (w >= M) return;
    const float* x = X + (long)w * 16;
    float a0 = 0.f, a1 = 0.f;
#pragma unroll
    for (int k = 0; k < 16; ++k) {
        float xv = x[k];
        a0 = fmaf(xv, W[k * 128 + lane], a0);
        a1 = fmaf(xv, W[k * 128 + 64 + lane], a1);
    }
    H[(long)w * 128 + lane] = f2bf(a0 + b[lane]);
    H[(long)w * 128 + 64 + lane] = f2bf(a1 + b[64 + lane]);
}

// ---------------- batched MFMA GEMM: O[g] = A[g] @ W[g], bf16 in/out ----------------
// grid.x tiles 64 rows, grid.y = which of 6 GEMMs. Block 256 = 4 waves; wave w:
// rows w*16..+15, all 128 cols (8 n-tiles), K=128 in 4 steps of 32.
__global__ __launch_bounds__(256) void gemm6_k(G6 g, int M) {
    __shared__ unsigned short Bt[128 * 136];  // W transposed [n][k], +8 pad (2-way only)
    int which = blockIdx.y;
    const unsigned short* A = g.A[which];
    const float* W = g.W[which];
    unsigned short* O = g.O[which];
    int tid = threadIdx.x;
#pragma unroll
    for (int i = 0; i < 64; ++i) {
        int idx = i * 256 + tid;
        int k = idx >> 7, c = idx & 127;
        Bt[c * 136 + k] = f2bf(W[idx]);
    }
    __syncthreads();
    int wv = tid >> 6, lane = tid & 63;
    int quad = lane >> 4, l15 = lane & 15;
    long rowbase = (long)blockIdx.x * 64 + wv * 16;
    long arow = rowbase + l15;
    if (arow > M - 1) arow = M - 1;  // clamp (ws-backed, safe)
    f32x4 acc[8];
#pragma unroll
    for (int n = 0; n < 8; ++n) acc[n] = (f32x4){0.f, 0.f, 0.f, 0.f};
#pragma unroll
    for (int kb = 0; kb < 4; ++kb) {
        short8 a = *(const short8*)(A + arow * 128 + kb * 32 + quad * 8);
#pragma unroll
        for (int n = 0; n < 8; ++n) {
            short8 b = *(const short8*)(&Bt[(n * 16 + l15) * 136 + kb * 32 + quad * 8]);
            acc[n] = __builtin_amdgcn_mfma_f32_16x16x32_bf16(a, b, acc[n], 0, 0, 0);
        }
    }
#pragma unroll
    for (int n = 0; n < 8; ++n)
#pragma unroll
        for (int r = 0; r < 4; ++r) {
            long row = rowbase + quad * 4 + r;
            if (row < M) O[row * 128 + n * 16 + l15] = f2bf(acc[n][r]);
        }
}

// ---------------- CSR build (once per call; reused by both layers) ----------------
__global__ void count_k(EPtrs ep, int* __restrict__ deg) {
    int r = blockIdx.y;
    int e = blockIdx.x * 256 + threadIdx.x;
    if (e >= NE) return;
    atomicAdd(&deg[r * NN + ep.p[r][NE + e]], 1);
}

__global__ void scanA_k(const int* __restrict__ deg, int* __restrict__ bsum) {
    __shared__ int sm[256];
    int r = blockIdx.y, b = blockIdx.x, t = threadIdx.x;
    int i = b * 256 + t;
    sm[t] = (i < NN) ? deg[r * NN + i] : 0;
    __syncthreads();
#pragma unroll
    for (int o = 128; o; o >>= 1) {
        if (t < o) sm[t] += sm[t + o];
        __syncthreads();
    }
    if (t == 0) bsum[r * NB + b] = sm[0];
}

__global__ void scanB_k(int* __restrict__ bsum) {
    __shared__ int sm[512];
    int r = blockIdx.x, t = threadIdx.x;
    int v = (t < NB) ? bsum[r * NB + t] : 0;
    sm[t] = v;
    __syncthreads();
    for (int o = 1; o < 512; o <<= 1) {
        int x = (t >= o) ? sm[t - o] : 0;
        __syncthreads();
        sm[t] += x;
        __syncthreads();
    }
    if (t < NB) bsum[r * NB + t] = sm[t] - v;
}

__global__ void scanC_k(int* __restrict__ deg, const int* __restrict__ bsum,
                        int* __restrict__ rowp) {
    __shared__ int sm[256];
    int r = blockIdx.y, b = blockIdx.x, t = threadIdx.x;
    int i = b * 256 + t;
    int v = (i < NN) ? deg[r * NN + i] : 0;
    sm[t] = v;
    __syncthreads();
    for (int o = 1; o < 256; o <<= 1) {
        int x = (t >= o) ? sm[t - o] : 0;
        __syncthreads();
        sm[t] += x;
        __syncthreads();
    }
    int excl = sm[t] - v + bsum[r * NB + b];
    if (i < NN) {
        rowp[r * (NN + 1) + i] = excl;
        deg[r * NN + i] = excl;  // becomes scatter cursor
        if (i == NN - 1) rowp[r * (NN + 1) + NN] = excl + v;
    }
}

__global__ void scat_k(EPtrs ep, int* __restrict__ cursor, int* __restrict__ csrc) {
    int r = blockIdx.y;
    int e = blockIdx.x * 256 + threadIdx.x;
    if (e >= NE) return;
    int s = ep.p[r][e], d = ep.p[r][NE + e];
    int pos = atomicAdd(&cursor[r * NN + d], 1);
    csrc[(long)r * NE + pos] = s;
}

// ---------- fused 3-relation GATv2 per dst node (online softmax, bias, relu) ----------
// One wave per dst node; lane c handles head0 ch c (col c) and head1 ch c (col 64+c).
__global__ void gat3_k(GatA g, float* __restrict__ outF, unsigned short* __restrict__ outH,
                       int mode) {  // mode 0: relu -> bf16 outH ; mode 1: fp32 outF
    int w = (int)((blockIdx.x * blockDim.x + threadIdx.x) >> 6);
    int c = threadIdx.x & 63;
    if (w >= NN) return;
    float acc0 = 0.f, acc1 = 0.f;
#pragma unroll
    for (int j = 0; j < 3; ++j) {
        const unsigned short* PL = g.PL[j];
        float gr0 = bf2f(g.PR[j][(long)w * 128 + c]);
        float gr1 = bf2f(g.PR[j][(long)w * 128 + 64 + c]);
        float at0 = g.att[j][c], at1 = g.att[j][64 + c];
        int beg = g.rowp[j][w], end = g.rowp[j][w + 1];
        float m0 = -1e30f, m1 = -1e30f, s0 = 0.f, s1 = 0.f, a0 = 0.f, a1 = 0.f;
        for (int i = beg; i < end; ++i) {
            int s = g.csrc[j][i];  // wave-uniform
            float gl0 = bf2f(PL[(long)s * 128 + c]);
            float gl1 = bf2f(PL[(long)s * 128 + 64 + c]);
            float v0 = gl0 + gr0;
            v0 = (v0 > 0.f ? v0 : 0.2f * v0) * at0;
            float v1 = gl1 + gr1;
            v1 = (v1 > 0.f ? v1 : 0.2f * v1) * at1;
#pragma unroll
            for (int o = 32; o; o >>= 1) {
                v0 += __shfl_xor(v0, o);
                v1 += __shfl_xor(v1, o);
            }
            float mn0 = fmaxf(m0, v0), sc0 = __expf(m0 - mn0), p0 = __expf(v0 - mn0);
            s0 = s0 * sc0 + p0; a0 = a0 * sc0 + p0 * gl0; m0 = mn0;
            float mn1 = fmaxf(m1, v1), sc1 = __expf(m1 - mn1), p1 = __expf(v1 - mn1);
            s1 = s1 * sc1 + p1; a1 = a1 * sc1 + p1 * gl1; m1 = mn1;
        }
        acc0 += a0 / (s0 + 1e-16f) + g.bias[j][c];
        acc1 += a1 / (s1 + 1e-16f) + g.bias[j][64 + c];
    }
    long o = (long)w * 128 + c;
    if (mode == 0) {
        outH[o] = f2bf(fmaxf(acc0, 0.f));
        outH[o + 64] = f2bf(fmaxf(acc1, 0.f));
    } else {
        outF[o] = acc0;
        outF[o + 64] = acc1;
    }
}

__global__ void sentinel_k(float* out) { out[0] = 123456.0f; }

extern "C" void kernel_launch(void* const* d_in, const int* in_sizes, int n_in,
                              void* d_out, int out_size, void* d_ws, size_t ws_size,
                              hipStream_t stream) {
    const float* xin[3] = {(const float*)d_in[0], (const float*)d_in[1], (const float*)d_in[2]};
    EPtrs ep;
    for (int r = 0; r < 9; ++r) ep.p[r] = (const int*)d_in[3 + r];
    const float* Win[3] = {(const float*)d_in[12], (const float*)d_in[14], (const float*)d_in[16]};
    const float* bin[3] = {(const float*)d_in[13], (const float*)d_in[15], (const float*)d_in[17]};
    const float* Wl[2] = {(const float*)d_in[18], (const float*)d_in[22]};
    const float* Wr[2] = {(const float*)d_in[19], (const float*)d_in[23]};
    const float* att[2] = {(const float*)d_in[20], (const float*)d_in[24]};
    const float* bc[2] = {(const float*)d_in[21], (const float*)d_in[25]};

    // ws: h1[3] h2[3] pl[3] pr[3] (bf16, NH each) | deg 9NN | bsum 9NB | rowp 9(NN+1) | csrc 9NE
    size_t nInt = (size_t)9 * NN + (size_t)9 * NB + (size_t)9 * (NN + 1) + (size_t)9 * NE;
    size_t need = (size_t)12 * NH * 2 + nInt * 4;
    if (ws_size < need) {
        hipMemsetAsync(d_out, 0, (size_t)out_size * 4, stream);
        sentinel_k<<<1, 1, 0, stream>>>((float*)d_out);
        return;
    }
    unsigned short* h1 = (unsigned short*)d_ws;
    unsigned short* h2 = h1 + (size_t)3 * NH;
    unsigned short* pl = h2 + (size_t)3 * NH;
    unsigned short* pr = pl + (size_t)3 * NH;
    int* deg = (int*)(pr + (size_t)3 * NH);
    int* bsum = deg + (size_t)9 * NN;
    int* rowp = bsum + (size_t)9 * NB;
    int* csrc = rowp + (size_t)9 * (NN + 1);

    static const int ST[9] = {0, 0, 1, 0, 2, 1, 2, 1, 2};
    static const int RT[3][3] = {{0, 2, 4}, {1, 6, 7}, {3, 5, 8}};  // relations per dst type

    for (int T = 0; T < 3; ++T)
        inproj_k<<<NN / 4, 256, 0, stream>>>(xin[T], Win[T], bin[T], h1 + (size_t)T * NH, NN);

    hipMemsetAsync(deg, 0, (size_t)9 * NN * 4, stream);
    dim3 eg((NE + 255) / 256, 9), ng(NB, 9);
    count_k<<<eg, 256, 0, stream>>>(ep, deg);
    scanA_k<<<ng, 256, 0, stream>>>(deg, bsum);
    scanB_k<<<9, 512, 0, stream>>>(bsum);
    scanC_k<<<ng, 256, 0, stream>>>(deg, bsum, rowp);
    scat_k<<<eg, 256, 0, stream>>>(ep, deg, csrc);

    dim3 gg((NN + 63) / 64, 6);
    for (int l = 0; l < 2; ++l) {
        unsigned short* hc = (l == 0) ? h1 : h2;
        for (int T = 0; T < 3; ++T) {
            G6 g6;
            GatA ga;
            for (int j = 0; j < 3; ++j) {
                int r = RT[T][j];
                g6.A[j] = hc + (size_t)ST[r] * NH;               // PL_j = h[src] @ Wl[r]
                g6.W[j] = Wl[l] + (size_t)r * 16384;
                g6.O[j] = pl + (size_t)j * NH;
                g6.A[3 + j] = hc + (size_t)T * NH;               // PR_j = h[T] @ Wr[r]
                g6.W[3 + j] = Wr[l] + (size_t)r * 16384;
                g6.O[3 + j] = pr + (size_t)j * NH;
                ga.PL[j] = pl + (size_t)j * NH;
                ga.PR[j] = pr + (size_t)j * NH;
                ga.rowp[j] = rowp + (size_t)r * (NN + 1);
                ga.csrc[j] = csrc + (size_t)r * NE;
                ga.att[j] = att[l] + (size_t)r * 128;
                ga.bias[j] = bc[l] + (size_t)r * 128;
            }
            gemm6_k<<<gg, 256, 0, stream>>>(g6, NN);
            if (l == 0)
                gat3_k<<<NN / 4, 256, 0, stream>>>(ga, nullptr, h2 + (size_t)T * NH, 0);
            else
                gat3_k<<<NN / 4, 256, 0, stream>>>(ga, (float*)d_out + (size_t)T * NH, nullptr, 1);
        }
    }
}